// Round 1
// baseline (2769.088 us; speedup 1.0000x reference)
//
#include <hip/hip_runtime.h>
#include <math.h>

#define B_ 8
#define T_ 2048
#define D_ 2048
#define H_ 128
#define M_ (B_ * T_)  // 16384 rows

// ---------------- projection GEMM: C[M,128] = X[M,2048] @ W[2048,128] ----------------
#define BM 64
#define BN 64
#define BK 16

__global__ __launch_bounds__(256) void proj_kernel(
    const float* __restrict__ X, const float* __restrict__ Wq,
    const float* __restrict__ Wk, const float* __restrict__ Wv,
    float* __restrict__ ws) {
  const int K = D_, N = H_;
  const float* W = (blockIdx.z == 0) ? Wq : (blockIdx.z == 1) ? Wk : Wv;
  float* C = ws + (size_t)blockIdx.z * (size_t)M_ * N;
  const int m0 = blockIdx.y * BM;
  const int n0 = blockIdx.x * BN;
  __shared__ float As[BK][BM + 4];  // +4 pad: keeps 16B alignment, breaks store conflicts
  __shared__ float Bs[BK][BN];
  const int tid = threadIdx.x;
  const int tx = tid & 15, ty = tid >> 4;
  const int a_row = tid >> 2, a_col = (tid & 3) << 2;   // A: 64 rows x 16 cols, float4 per thread
  const int b_row = tid >> 4, b_col = (tid & 15) << 2;  // B: 16 rows x 64 cols, float4 per thread
  const float* Aptr = X + (size_t)(m0 + a_row) * K + a_col;
  const float* Bptr = W + (size_t)b_row * N + n0 + b_col;
  float acc[4][4] = {};
  for (int k0 = 0; k0 < K; k0 += BK) {
    float4 av = *(const float4*)(Aptr + k0);
    float4 bv = *(const float4*)(Bptr + (size_t)k0 * N);
    As[a_col + 0][a_row] = av.x;
    As[a_col + 1][a_row] = av.y;
    As[a_col + 2][a_row] = av.z;
    As[a_col + 3][a_row] = av.w;
    *(float4*)&Bs[b_row][b_col] = bv;
    __syncthreads();
#pragma unroll
    for (int kk = 0; kk < BK; ++kk) {
      float4 a = *(const float4*)&As[kk][ty << 2];
      float4 b = *(const float4*)&Bs[kk][tx << 2];
      float ar[4] = {a.x, a.y, a.z, a.w};
      float br[4] = {b.x, b.y, b.z, b.w};
#pragma unroll
      for (int i = 0; i < 4; ++i)
#pragma unroll
        for (int j = 0; j < 4; ++j) acc[i][j] += ar[i] * br[j];
    }
    __syncthreads();
  }
#pragma unroll
  for (int i = 0; i < 4; ++i) {
    float4 r = make_float4(acc[i][0], acc[i][1], acc[i][2], acc[i][3]);
    *(float4*)&C[(size_t)(m0 + (ty << 2) + i) * N + n0 + (tx << 2)] = r;
  }
}

// ---------------- flash attention, fp32, online softmax ----------------
// block = 256 threads; handles AQ=16 queries of one batch. Thread (qi = tid/16,
// dg = tid%16) owns output dims {dg*4..dg*4+3, 64+dg*4..+3} of query qi.
#define AQ 16
#define AK 16

__global__ __launch_bounds__(256) void attn_kernel(
    const float* __restrict__ ws, float* __restrict__ out) {
  const int b = blockIdx.y;
  const int t0 = blockIdx.x * AQ;
  const float* qb = ws + ((size_t)b * T_) * H_;
  const float* kb = ws + (size_t)M_ * H_ + ((size_t)b * T_) * H_;
  const float* vb = ws + 2 * (size_t)M_ * H_ + ((size_t)b * T_) * H_;
  __shared__ float qs[AQ][H_];
  __shared__ float ks[AK][H_];
  __shared__ float vs[AK][H_];
  __shared__ float ss[AQ][AK];
  const int tid = threadIdx.x;
  const int qi = tid >> 4;
  const int dg = tid & 15;
  // stage the q tile (2048 floats = 512 float4, 2 per thread, coalesced)
  {
    const float4* src = (const float4*)(qb + (size_t)t0 * H_);
    float4* dst = (float4*)&qs[0][0];
    dst[tid] = src[tid];
    dst[tid + 256] = src[tid + 256];
  }
  float accv[8] = {};
  float m = -INFINITY, l = 0.f;
  const float scale = 11.313708498984761f;  // sqrt(128), reference MULTIPLIES by sqrt(H)
  for (int kt = 0; kt < t0 + AQ; kt += AK) {
    __syncthreads();  // prior iter's ss/vs reads done (and iter0: qs store done)
    {
      const float4* srck = (const float4*)(kb + (size_t)kt * H_);
      const float4* srcv = (const float4*)(vb + (size_t)kt * H_);
      float4* dk = (float4*)&ks[0][0];
      float4* dv = (float4*)&vs[0][0];
      dk[tid] = srck[tid];
      dk[tid + 256] = srck[tid + 256];
      dv[tid] = srcv[tid];
      dv[tid + 256] = srcv[tid + 256];
    }
    __syncthreads();
    // scores: thread computes s[qi][dg] = scale * <q[qi], k[dg]>
    {
      float s = 0.f;
      const float4* qr = (const float4*)&qs[qi][0];  // broadcast across 16 lanes
      const float4* kr = (const float4*)&ks[dg][0];  // 2-way bank alias (free)
#pragma unroll
      for (int h4 = 0; h4 < H_ / 4; ++h4) {
        float4 a = qr[h4];
        float4 c = kr[h4];
        s += a.x * c.x + a.y * c.y + a.z * c.z + a.w * c.w;
      }
      s *= scale;
      if (kt + dg > t0 + qi) s = -1e30f;  // causal mask; exp underflows to exact 0
      ss[qi][dg] = s;
    }
    __syncthreads();
    // online softmax update (each of the 16 threads of a query redundantly)
    float mnew = m;
#pragma unroll
    for (int j = 0; j < AK; ++j) mnew = fmaxf(mnew, ss[qi][j]);
    float alpha = expf(m - mnew);  // m=-inf first iter -> alpha=0
    m = mnew;
    float p[AK];
    float lsum = 0.f;
#pragma unroll
    for (int j = 0; j < AK; ++j) {
      p[j] = expf(ss[qi][j] - mnew);
      lsum += p[j];
    }
    l = l * alpha + lsum;
#pragma unroll
    for (int d = 0; d < 8; ++d) accv[d] *= alpha;
#pragma unroll
    for (int j = 0; j < AK; ++j) {
      float4 v0 = *(const float4*)&vs[j][dg << 2];         // 2-way alias (free)
      float4 v1 = *(const float4*)&vs[j][64 + (dg << 2)];  // 2-way alias (free)
      accv[0] += p[j] * v0.x;
      accv[1] += p[j] * v0.y;
      accv[2] += p[j] * v0.z;
      accv[3] += p[j] * v0.w;
      accv[4] += p[j] * v1.x;
      accv[5] += p[j] * v1.y;
      accv[6] += p[j] * v1.z;
      accv[7] += p[j] * v1.w;
    }
  }
  const float inv_l = 1.0f / l;
  float* orow = out + (((size_t)b * T_ + t0 + qi) * (size_t)H_);
  float4 o0 = make_float4(accv[0] * inv_l, accv[1] * inv_l, accv[2] * inv_l,
                          accv[3] * inv_l);
  float4 o1 = make_float4(accv[4] * inv_l, accv[5] * inv_l, accv[6] * inv_l,
                          accv[7] * inv_l);
  *(float4*)&orow[dg << 2] = o0;
  *(float4*)&orow[64 + (dg << 2)] = o1;
}

extern "C" void kernel_launch(void* const* d_in, const int* in_sizes, int n_in,
                              void* d_out, int out_size, void* d_ws, size_t ws_size,
                              hipStream_t stream) {
  const float* x = (const float*)d_in[0];
  const float* Wq = (const float*)d_in[1];
  const float* Wk = (const float*)d_in[2];
  const float* Wv = (const float*)d_in[3];
  float* ws = (float*)d_ws;   // q | k | v : 3 * 16384*128 floats = 25.2 MB
  float* out = (float*)d_out;
  dim3 pgrid(H_ / BN, M_ / BM, 3);  // (2, 256, 3)
  proj_kernel<<<pgrid, 256, 0, stream>>>(x, Wq, Wk, Wv, ws);
  dim3 agrid(T_ / AQ, B_);  // (128, 8)
  attn_kernel<<<agrid, 256, 0, stream>>>(ws, out);
}

// Round 2
// 960.440 us; speedup vs baseline: 2.8831x; 2.8831x over previous
//
#include <hip/hip_runtime.h>
#include <math.h>

#define B_ 8
#define T_ 2048
#define D_ 2048
#define H_ 128
#define M_ (B_ * T_)

// ---------- fused projection GEMM: for z in {q,k,v}: ws_z = X @ W_z ----------
// BM=64, BN=64, BK=32; 256 threads; 4x4 microtile; z-loop inside so the A tile
// is staged once for all three weight matrices.
#define PBM 64
#define PBN 64
#define PBK 32
#define ASTR 68  // As row stride (floats); 68%8=4 -> rows spread bank quads
#define BSTR 68

__global__ __launch_bounds__(256) void proj_kernel(
    const float* __restrict__ X, const float* __restrict__ Wq,
    const float* __restrict__ Wk, const float* __restrict__ Wv,
    float* __restrict__ ws) {
  __shared__ float As[PBK * ASTR];     // As[kk][m] (transposed A tile)
  __shared__ float Bs[3][PBK * BSTR];  // Bs[z][kk][n]
  const float* Ws[3] = {Wq, Wk, Wv};
  const int m0 = blockIdx.y * PBM;
  const int n0 = blockIdx.x * PBN;
  const int t = threadIdx.x;
  const int tx = t & 15;  // n-group: cols tx*4..+3
  const int mg = t >> 4;  // m-group: rows mg*4..+3
  float acc[3][4][4] = {};
  for (int k0 = 0; k0 < D_; k0 += PBK) {
    __syncthreads();
    {  // stage A (64 m x 32 k), transposed
      int f = t;
#pragma unroll
      for (int it = 0; it < 2; ++it, f += 256) {
        int row = f >> 3, c4 = (f & 7) << 2;
        float4 v = *(const float4*)&X[(size_t)(m0 + row) * D_ + k0 + c4];
        As[(c4 + 0) * ASTR + row] = v.x;
        As[(c4 + 1) * ASTR + row] = v.y;
        As[(c4 + 2) * ASTR + row] = v.z;
        As[(c4 + 3) * ASTR + row] = v.w;
      }
    }
#pragma unroll
    for (int z = 0; z < 3; ++z) {  // stage B for 3 matrices (32 k x 64 n)
      int f = t;
#pragma unroll
      for (int it = 0; it < 2; ++it, f += 256) {
        int row = f >> 4, c4 = (f & 15) << 2;
        *(float4*)&Bs[z][row * BSTR + c4] =
            *(const float4*)&Ws[z][(size_t)(k0 + row) * H_ + n0 + c4];
      }
    }
    __syncthreads();
#pragma unroll
    for (int kk = 0; kk < PBK; ++kk) {
      float4 a = *(const float4*)&As[kk * ASTR + (mg << 2)];  // 4-way bcast
      float ar[4] = {a.x, a.y, a.z, a.w};
#pragma unroll
      for (int z = 0; z < 3; ++z) {
        float4 b = *(const float4*)&Bs[z][kk * BSTR + (tx << 2)];
        float br[4] = {b.x, b.y, b.z, b.w};
#pragma unroll
        for (int i = 0; i < 4; ++i)
#pragma unroll
          for (int j = 0; j < 4; ++j) acc[z][i][j] += ar[i] * br[j];
      }
    }
  }
#pragma unroll
  for (int z = 0; z < 3; ++z)
#pragma unroll
    for (int i = 0; i < 4; ++i) {
      float4 r = make_float4(acc[z][i][0], acc[z][i][1], acc[z][i][2],
                             acc[z][i][3]);
      *(float4*)&ws[(size_t)z * M_ * H_ +
                    (size_t)(m0 + (mg << 2) + i) * H_ + n0 + (tx << 2)] = r;
    }
}

// ---------- flash attention, fp32, register-tiled ----------
// 256 threads; AQ=32 queries, KT=32 keys per tile. QK microtile 4q x 1k
// (q broadcast), PV microtile 4q x 4h. All LDS strides avoid 32-bank aliasing.
#define AQ 32
#define KT 32
#define QSTR 132  // 128+4: rows spread bank quads
#define SSTR 36   // 32+4

__global__ __launch_bounds__(256) void attn_kernel(
    const float* __restrict__ ws, float* __restrict__ out) {
  const int b = blockIdx.y;
  const int x = blockIdx.x;
  // complementary work pairing: blocks i and i+256 in dispatch order get
  // q-tiles whose causal work sums to a constant -> CU load balance
  const int qt = (b < 4) ? (63 - x) : x;
  const int t0 = qt * AQ;
  const float* qb = ws + (size_t)b * T_ * H_;
  const float* kb = ws + (size_t)M_ * H_ + (size_t)b * T_ * H_;
  const float* vb = ws + 2 * (size_t)M_ * H_ + (size_t)b * T_ * H_;
  __shared__ float qs[AQ * QSTR];
  __shared__ float ks[KT * QSTR];
  __shared__ float vs[KT * QSTR];
  __shared__ float ss[AQ * SSTR];
  __shared__ float m_s[AQ], l_s[AQ], a_s[AQ];
  const int t = threadIdx.x;
  const int qg = t >> 5;  // 0..7: q-rows qg+8i
  const int lg = t & 31;  // QK: k-col; PV: h-group (cols lg*4..+3)
  {  // stage Q (32 x 128)
    int f = t;
#pragma unroll
    for (int it = 0; it < 4; ++it, f += 256) {
      int row = f >> 5, c4 = (f & 31) << 2;
      *(float4*)&qs[row * QSTR + c4] =
          *(const float4*)&qb[(size_t)(t0 + row) * H_ + c4];
    }
  }
  if (t < AQ) {
    m_s[t] = -INFINITY;
    l_s[t] = 0.f;
  }
  float oacc[4][4] = {};
  const int nk = t0 / KT + 1;
  for (int kt_i = 0; kt_i < nk; ++kt_i) {
    const int kt = kt_i * KT;
    __syncthreads();  // prior tile's PV reads of ss/vs complete
    {                 // stage K,V (32 x 128 each)
      int f = t;
#pragma unroll
      for (int it = 0; it < 4; ++it, f += 256) {
        int row = f >> 5, c4 = (f & 31) << 2;
        *(float4*)&ks[row * QSTR + c4] =
            *(const float4*)&kb[(size_t)(kt + row) * H_ + c4];
        *(float4*)&vs[row * QSTR + c4] =
            *(const float4*)&vb[(size_t)(kt + row) * H_ + c4];
      }
    }
    __syncthreads();
    {  // QK: s[qg+8i][lg]
      float s4[4] = {};
#pragma unroll
      for (int h4 = 0; h4 < H_ / 4; ++h4) {
        float4 kv = *(const float4*)&ks[lg * QSTR + (h4 << 2)];
#pragma unroll
        for (int i = 0; i < 4; ++i) {
          float4 qv = *(const float4*)&qs[(qg + 8 * i) * QSTR + (h4 << 2)];
          s4[i] += qv.x * kv.x + qv.y * kv.y + qv.z * kv.z + qv.w * kv.w;
        }
      }
      const float scale = 11.313708498984761f;  // sqrt(128), ref multiplies
      const bool maskt = (kt + KT > t0);        // only the diagonal tile
#pragma unroll
      for (int i = 0; i < 4; ++i) {
        float s = s4[i] * scale;
        if (maskt && (kt + lg > t0 + qg + 8 * i)) s = -1e30f;
        ss[(qg + 8 * i) * SSTR + lg] = s;
      }
    }
    __syncthreads();
    {  // softmax: 8 threads per q-row, shuffle butterfly
      int r = t >> 3, cg = (t & 7) << 2;
      float4 sv = *(const float4*)&ss[r * SSTR + cg];
      float tm = fmaxf(fmaxf(sv.x, sv.y), fmaxf(sv.z, sv.w));
      tm = fmaxf(tm, __shfl_xor(tm, 1));
      tm = fmaxf(tm, __shfl_xor(tm, 2));
      tm = fmaxf(tm, __shfl_xor(tm, 4));
      float mold = m_s[r];
      float mnew = fmaxf(mold, tm);
      float4 p;
      p.x = __expf(sv.x - mnew);
      p.y = __expf(sv.y - mnew);
      p.z = __expf(sv.z - mnew);
      p.w = __expf(sv.w - mnew);
      *(float4*)&ss[r * SSTR + cg] = p;
      float psum = p.x + p.y + p.z + p.w;
      psum += __shfl_xor(psum, 1);
      psum += __shfl_xor(psum, 2);
      psum += __shfl_xor(psum, 4);
      if ((t & 7) == 0) {
        float alpha = __expf(mold - mnew);  // exp(-inf)=0 on first tile
        a_s[r] = alpha;
        m_s[r] = mnew;
        l_s[r] = l_s[r] * alpha + psum;
      }
    }
    __syncthreads();
    {  // PV: oacc[i][j] for rows qg+8i, cols lg*4+j
#pragma unroll
      for (int i = 0; i < 4; ++i) {
        float al = a_s[qg + 8 * i];
#pragma unroll
        for (int j = 0; j < 4; ++j) oacc[i][j] *= al;
      }
#pragma unroll
      for (int k4 = 0; k4 < KT / 4; ++k4) {
        float4 v0 = *(const float4*)&vs[(k4 * 4 + 0) * QSTR + (lg << 2)];
        float4 v1 = *(const float4*)&vs[(k4 * 4 + 1) * QSTR + (lg << 2)];
        float4 v2 = *(const float4*)&vs[(k4 * 4 + 2) * QSTR + (lg << 2)];
        float4 v3 = *(const float4*)&vs[(k4 * 4 + 3) * QSTR + (lg << 2)];
#pragma unroll
        for (int i = 0; i < 4; ++i) {
          float4 p = *(const float4*)&ss[(qg + 8 * i) * SSTR + (k4 << 2)];
          oacc[i][0] += p.x * v0.x + p.y * v1.x + p.z * v2.x + p.w * v3.x;
          oacc[i][1] += p.x * v0.y + p.y * v1.y + p.z * v2.y + p.w * v3.y;
          oacc[i][2] += p.x * v0.z + p.y * v1.z + p.z * v2.z + p.w * v3.z;
          oacc[i][3] += p.x * v0.w + p.y * v1.w + p.z * v2.w + p.w * v3.w;
        }
      }
    }
  }
#pragma unroll
  for (int i = 0; i < 4; ++i) {  // epilogue: O = acc / l
    int r = qg + 8 * i;
    float inv = 1.0f / l_s[r];
    float4 o = make_float4(oacc[i][0] * inv, oacc[i][1] * inv,
                           oacc[i][2] * inv, oacc[i][3] * inv);
    *(float4*)&out[((size_t)b * T_ + t0 + r) * H_ + (lg << 2)] = o;
  }
}

extern "C" void kernel_launch(void* const* d_in, const int* in_sizes, int n_in,
                              void* d_out, int out_size, void* d_ws, size_t ws_size,
                              hipStream_t stream) {
  const float* x = (const float*)d_in[0];
  const float* Wq = (const float*)d_in[1];
  const float* Wk = (const float*)d_in[2];
  const float* Wv = (const float*)d_in[3];
  float* ws = (float*)d_ws;  // q | k | v : 3 * 16384*128 floats = 25.2 MB
  float* out = (float*)d_out;
  dim3 pgrid(H_ / PBN, M_ / PBM);  // (2, 256)
  proj_kernel<<<pgrid, 256, 0, stream>>>(x, Wq, Wk, Wv, ws);
  dim3 agrid(T_ / AQ, B_);  // (64, 8)
  attn_kernel<<<agrid, 256, 0, stream>>>(ws, out);
}

// Round 3
// 456.953 us; speedup vs baseline: 6.0599x; 2.1018x over previous
//
#include <hip/hip_runtime.h>
#include <math.h>

#define B_ 8
#define T_ 2048
#define D_ 2048
#define H_ 128
#define M_ (B_ * T_)

typedef __bf16 bf16x8 __attribute__((ext_vector_type(8)));
typedef __bf16 bf16x4 __attribute__((ext_vector_type(4)));
typedef float f32x4 __attribute__((ext_vector_type(4)));

#define MFMA(a, b, c) __builtin_amdgcn_mfma_f32_16x16x32_bf16(a, b, c, 0, 0, 0)

// ws layout (bf16 elements)
#define QH_OFF 0
#define QL_OFF (1 * 2097152)  // M_*H_ = 16384*128
#define KH_OFF (2 * 2097152)
#define KL_OFF (3 * 2097152)
#define VT_OFF (4 * 2097152)         // vt[b][h][t]
#define WTH_OFF (5 * 2097152)        // wt_hi[z*128+n][k]
#define WTL_OFF (WTH_OFF + 786432)   // 3*128*2048

// ---------------- prep: W[k][n] fp32 -> Wt_hi/lo[n][k] bf16 ----------------
__global__ __launch_bounds__(256) void prep_kernel(
    const float* __restrict__ Wq, const float* __restrict__ Wk,
    const float* __restrict__ Wv, __bf16* __restrict__ wt_hi,
    __bf16* __restrict__ wt_lo) {
  const int z = blockIdx.y;
  const int k0 = blockIdx.x * 64;
  const float* W = z == 0 ? Wq : z == 1 ? Wk : Wv;
  __shared__ float tile[64][132];
  const int t = threadIdx.x;
#pragma unroll
  for (int it = 0; it < 8; ++it) {
    int f4 = it * 256 + t;  // 2048 float4 = 64 rows x 32
    int row = f4 >> 5, c = (f4 & 31) << 2;
    *(float4*)&tile[row][c] = *(const float4*)&W[(size_t)(k0 + row) * H_ + c];
  }
  __syncthreads();
  int n = t >> 1, kh = (t & 1) << 5;
  __bf16 h[32], l[32];
#pragma unroll
  for (int kk = 0; kk < 32; ++kk) {
    float x = tile[kh + kk][n];
    __bf16 hi = (__bf16)x;
    h[kk] = hi;
    l[kk] = (__bf16)(x - (float)hi);
  }
  size_t base = (size_t)(z * H_ + n) * D_ + k0 + kh;
#pragma unroll
  for (int c = 0; c < 4; ++c) {
    *(bf16x8*)&wt_hi[base + c * 8] = *(bf16x8*)&h[c * 8];
    *(bf16x8*)&wt_lo[base + c * 8] = *(bf16x8*)&l[c * 8];
  }
}

// ---------------- proj: [q|k|v] = X @ [Wq|Wk|Wv], split-bf16 3-pass MFMA ----
// grid (2 n-strips, 256 m-tiles), 256 thr. Wave w: 64m x 48n (4mg x 3nt tiles).
__global__ __launch_bounds__(256, 2) void proj_kernel(
    const float* __restrict__ X, const __bf16* __restrict__ wt_hi,
    const __bf16* __restrict__ wt_lo, __bf16* __restrict__ qh,
    __bf16* __restrict__ ql, __bf16* __restrict__ kh,
    __bf16* __restrict__ kl, __bf16* __restrict__ vt) {
  const int strip = blockIdx.x;
  const int m0 = blockIdx.y * 64;
  __shared__ __align__(16) __bf16 Xh[64 * 40];  // stride 40 elem = 80B
  __shared__ __align__(16) __bf16 Xl[64 * 40];
  const int t = threadIdx.x;
  const int wave = t >> 6, lane = t & 63;
  const int l15 = lane & 15, quad = lane >> 4;
  const int nb = strip * 192 + wave * 48;
  f32x4 acc[4][3] = {};
  const int sm = t >> 2, skc = (t & 3) << 3;  // staging: row, k-offset
  for (int k0 = 0; k0 < D_; k0 += 32) {
    __syncthreads();
    {  // stage X 64x32 fp32 -> hi/lo bf16
      const float* xp = X + (size_t)(m0 + sm) * D_ + k0 + skc;
      float4 a = *(const float4*)xp;
      float4 b = *(const float4*)(xp + 4);
      __bf16 h0 = (__bf16)a.x, h1 = (__bf16)a.y, h2 = (__bf16)a.z, h3 = (__bf16)a.w;
      __bf16 h4 = (__bf16)b.x, h5 = (__bf16)b.y, h6 = (__bf16)b.z, h7 = (__bf16)b.w;
      *(bf16x4*)&Xh[sm * 40 + skc] = (bf16x4){h0, h1, h2, h3};
      *(bf16x4*)&Xh[sm * 40 + skc + 4] = (bf16x4){h4, h5, h6, h7};
      *(bf16x4*)&Xl[sm * 40 + skc] =
          (bf16x4){(__bf16)(a.x - (float)h0), (__bf16)(a.y - (float)h1),
                   (__bf16)(a.z - (float)h2), (__bf16)(a.w - (float)h3)};
      *(bf16x4*)&Xl[sm * 40 + skc + 4] =
          (bf16x4){(__bf16)(b.x - (float)h4), (__bf16)(b.y - (float)h5),
                   (__bf16)(b.z - (float)h6), (__bf16)(b.w - (float)h7)};
    }
    __syncthreads();
    bf16x8 ah[4], al[4];
#pragma unroll
    for (int mg = 0; mg < 4; ++mg) {
      ah[mg] = *(bf16x8*)&Xh[(mg * 16 + l15) * 40 + quad * 8];
      al[mg] = *(bf16x8*)&Xl[(mg * 16 + l15) * 40 + quad * 8];
    }
#pragma unroll
    for (int nt = 0; nt < 3; ++nt) {
      size_t woff = (size_t)(nb + nt * 16 + l15) * D_ + k0 + quad * 8;
      bf16x8 bh = *(const bf16x8*)(wt_hi + woff);
      bf16x8 bl = *(const bf16x8*)(wt_lo + woff);
#pragma unroll
      for (int mg = 0; mg < 4; ++mg) {
        acc[mg][nt] = MFMA(ah[mg], bh, acc[mg][nt]);
        acc[mg][nt] = MFMA(al[mg], bh, acc[mg][nt]);
        acc[mg][nt] = MFMA(ah[mg], bl, acc[mg][nt]);
      }
    }
  }
  // epilogue
#pragma unroll
  for (int nt = 0; nt < 3; ++nt) {
    int ncb = nb + nt * 16;  // wave-uniform tile base; never crosses z
    int z = ncb >> 7;
    int h = (ncb & 127) + l15;
#pragma unroll
    for (int mg = 0; mg < 4; ++mg) {
      int r0 = m0 + mg * 16 + quad * 4;
      if (z == 2) {
        int b = m0 >> 11;
        int tt0 = (m0 & 2047) + mg * 16 + quad * 4;
        bf16x4 pv = {(__bf16)acc[mg][nt][0], (__bf16)acc[mg][nt][1],
                     (__bf16)acc[mg][nt][2], (__bf16)acc[mg][nt][3]};
        *(bf16x4*)&vt[(size_t)(b * H_ + h) * T_ + tt0] = pv;
      } else {
        __bf16* dh = z == 0 ? qh : kh;
        __bf16* dl = z == 0 ? ql : kl;
#pragma unroll
        for (int reg = 0; reg < 4; ++reg) {
          float v = acc[mg][nt][reg];
          __bf16 hi = (__bf16)v;
          dh[(size_t)(r0 + reg) * H_ + h] = hi;
          dl[(size_t)(r0 + reg) * H_ + h] = (__bf16)(v - (float)hi);
        }
      }
    }
  }
}

// ---------------- attention: flash, split-bf16 QK (3-pass), bf16 PV --------
// 256 blocks x 512 thr (8 waves). Block: complementary subtile pair
// (ql, 63-ql) of one batch -> constant 33 tiles of work per block.
// Waves 0-3 -> subtile A, 4-7 -> B; wave takes key-tiles cw, cw+4, ...
__global__ __launch_bounds__(512, 2) void attn_kernel(
    const __bf16* __restrict__ qh, const __bf16* __restrict__ qlo,
    const __bf16* __restrict__ kh, const __bf16* __restrict__ klo,
    const __bf16* __restrict__ vt, float* __restrict__ out) {
  const int t = threadIdx.x;
  const int wv = t >> 6, st = wv >> 2, cw = wv & 3;
  const int lane = t & 63, l15 = lane & 15, quad = lane >> 4;
  const int j = blockIdx.x, b = j >> 5, pi = j & 31;
  const int qlidx = (st == 0) ? pi : 63 - pi;
  const int t0 = qlidx * 32;
  const int nkt = (qlidx >> 1) + 1;
  __shared__ __align__(16) __bf16 Pbuf[8][32 * 72];  // stride 72 = 144B
  __shared__ __align__(16) float Obuf[2][32 * 132];
  __shared__ float mlb[2][4][32], llb[2][4][32];
  const size_t qrow0 = (size_t)b * T_ + t0;
  // Q fragments resident in registers (hi+lo)
  bf16x8 qfh[2][4], qfl[2][4];
#pragma unroll
  for (int mg = 0; mg < 2; ++mg)
#pragma unroll
    for (int ds = 0; ds < 4; ++ds) {
      size_t off = (qrow0 + mg * 16 + l15) * H_ + ds * 32 + quad * 8;
      qfh[mg][ds] = *(const bf16x8*)(qh + off);
      qfl[mg][ds] = *(const bf16x8*)(qlo + off);
    }
  f32x4 O[2][8] = {};
  float ms[2][4], ls[2][4];
#pragma unroll
  for (int mg = 0; mg < 2; ++mg)
#pragma unroll
    for (int reg = 0; reg < 4; ++reg) {
      ms[mg][reg] = -INFINITY;
      ls[mg][reg] = 0.f;
    }
  const __bf16* vtb = vt + (size_t)b * H_ * T_;
  const float scale = 11.313708498984761f;  // sqrt(128); ref multiplies
  for (int kt_i = cw; kt_i < nkt; kt_i += 4) {
    const int kt = kt_i * 64;
    f32x4 S[2][4] = {};
#pragma unroll
    for (int ds = 0; ds < 4; ++ds)
#pragma unroll
      for (int ct = 0; ct < 4; ++ct) {
        size_t koff =
            ((size_t)b * T_ + kt + ct * 16 + l15) * H_ + ds * 32 + quad * 8;
        bf16x8 bh = *(const bf16x8*)(kh + koff);
        bf16x8 bl = *(const bf16x8*)(klo + koff);
#pragma unroll
        for (int mg = 0; mg < 2; ++mg) {
          S[mg][ct] = MFMA(qfh[mg][ds], bh, S[mg][ct]);
          S[mg][ct] = MFMA(qfl[mg][ds], bh, S[mg][ct]);
          S[mg][ct] = MFMA(qfh[mg][ds], bl, S[mg][ct]);
        }
      }
    const bool diag = (kt_i == nkt - 1);
#pragma unroll
    for (int mg = 0; mg < 2; ++mg)
#pragma unroll
      for (int ct = 0; ct < 4; ++ct)
#pragma unroll
        for (int reg = 0; reg < 4; ++reg) {
          float s = S[mg][ct][reg] * scale;
          if (diag && (kt + ct * 16 + l15 > t0 + mg * 16 + quad * 4 + reg))
            s = -1e30f;
          S[mg][ct][reg] = s;
        }
    float al_[2][4];
#pragma unroll
    for (int mg = 0; mg < 2; ++mg)
#pragma unroll
      for (int reg = 0; reg < 4; ++reg) {
        float r = fmaxf(fmaxf(S[mg][0][reg], S[mg][1][reg]),
                        fmaxf(S[mg][2][reg], S[mg][3][reg]));
        r = fmaxf(r, __shfl_xor(r, 1));
        r = fmaxf(r, __shfl_xor(r, 2));
        r = fmaxf(r, __shfl_xor(r, 4));
        r = fmaxf(r, __shfl_xor(r, 8));
        float mn = fmaxf(ms[mg][reg], r);
        float a = __expf(ms[mg][reg] - mn);
        ms[mg][reg] = mn;
        float ps = 0.f;
#pragma unroll
        for (int ct = 0; ct < 4; ++ct) {
          float p = __expf(S[mg][ct][reg] - mn);
          S[mg][ct][reg] = p;
          ps += p;
        }
        ps += __shfl_xor(ps, 1);
        ps += __shfl_xor(ps, 2);
        ps += __shfl_xor(ps, 4);
        ps += __shfl_xor(ps, 8);
        ls[mg][reg] = ls[mg][reg] * a + ps;
        al_[mg][reg] = a;
      }
#pragma unroll
    for (int mg = 0; mg < 2; ++mg)
#pragma unroll
      for (int ht = 0; ht < 8; ++ht)
#pragma unroll
        for (int reg = 0; reg < 4; ++reg) O[mg][ht][reg] *= al_[mg][reg];
    // P (C-layout) -> LDS -> A-layout, bf16
#pragma unroll
    for (int mg = 0; mg < 2; ++mg)
#pragma unroll
      for (int ct = 0; ct < 4; ++ct)
#pragma unroll
        for (int reg = 0; reg < 4; ++reg)
          Pbuf[wv][(mg * 16 + quad * 4 + reg) * 72 + ct * 16 + l15] =
              (__bf16)S[mg][ct][reg];
#pragma unroll
    for (int ks = 0; ks < 2; ++ks) {
      bf16x8 pf0 = *(bf16x8*)&Pbuf[wv][(l15)*72 + ks * 32 + quad * 8];
      bf16x8 pf1 = *(bf16x8*)&Pbuf[wv][(16 + l15) * 72 + ks * 32 + quad * 8];
#pragma unroll
      for (int ht = 0; ht < 8; ++ht) {
        bf16x8 vf = *(const bf16x8*)&vtb[(size_t)(ht * 16 + l15) * T_ + kt +
                                         ks * 32 + quad * 8];
        O[0][ht] = MFMA(pf0, vf, O[0][ht]);
        O[1][ht] = MFMA(pf1, vf, O[1][ht]);
      }
    }
  }
  // -------- merge the 4 key-chunk waves of each subtile --------
  if (l15 == 0) {
#pragma unroll
    for (int mg = 0; mg < 2; ++mg)
#pragma unroll
      for (int reg = 0; reg < 4; ++reg) {
        mlb[st][cw][mg * 16 + quad * 4 + reg] = ms[mg][reg];
        llb[st][cw][mg * 16 + quad * 4 + reg] = ls[mg][reg];
      }
  }
  for (int i = t; i < 2 * 32 * 132; i += 512) ((float*)Obuf)[i] = 0.f;
  __syncthreads();
  float aw[2][4];
#pragma unroll
  for (int mg = 0; mg < 2; ++mg)
#pragma unroll
    for (int reg = 0; reg < 4; ++reg) {
      int row = mg * 16 + quad * 4 + reg;
      float M = fmaxf(fmaxf(mlb[st][0][row], mlb[st][1][row]),
                      fmaxf(mlb[st][2][row], mlb[st][3][row]));
      float L = 0.f;
#pragma unroll
      for (int w = 0; w < 4; ++w)
        L += llb[st][w][row] * __expf(mlb[st][w][row] - M);
      aw[mg][reg] = __expf(ms[mg][reg] - M) / L;
    }
#pragma unroll
  for (int mg = 0; mg < 2; ++mg)
#pragma unroll
    for (int ht = 0; ht < 8; ++ht)
#pragma unroll
      for (int reg = 0; reg < 4; ++reg)
        atomicAdd(&Obuf[st][(mg * 16 + quad * 4 + reg) * 132 + ht * 16 + l15],
                  O[mg][ht][reg] * aw[mg][reg]);
  __syncthreads();
  // -------- write out (fp32, coalesced) --------
  {
    const int stw = t >> 8, tt = t & 255;
    const int qlw = (stw == 0) ? pi : 63 - pi;
    const size_t obase = ((size_t)b * T_ + qlw * 32) * H_;
#pragma unroll
    for (int i = 0; i < 4; ++i) {
      int f4 = i * 256 + tt;  // 1024 float4 = 32 rows x 32
      int row = f4 >> 5, c = (f4 & 31) << 2;
      *(float4*)&out[obase + (size_t)row * H_ + c] =
          *(float4*)&Obuf[stw][row * 132 + c];
    }
  }
}

extern "C" void kernel_launch(void* const* d_in, const int* in_sizes, int n_in,
                              void* d_out, int out_size, void* d_ws, size_t ws_size,
                              hipStream_t stream) {
  const float* x = (const float*)d_in[0];
  const float* Wq = (const float*)d_in[1];
  const float* Wk = (const float*)d_in[2];
  const float* Wv = (const float*)d_in[3];
  __bf16* ws = (__bf16*)d_ws;
  float* out = (float*)d_out;
  prep_kernel<<<dim3(32, 3), 256, 0, stream>>>(Wq, Wk, Wv, ws + WTH_OFF,
                                               ws + WTL_OFF);
  proj_kernel<<<dim3(2, 256), 256, 0, stream>>>(
      x, ws + WTH_OFF, ws + WTL_OFF, ws + QH_OFF, ws + QL_OFF, ws + KH_OFF,
      ws + KL_OFF, ws + VT_OFF);
  attn_kernel<<<256, 512, 0, stream>>>(ws + QH_OFF, ws + QL_OFF, ws + KH_OFF,
                                       ws + KL_OFF, ws + VT_OFF, out);
}